// Round 2
// baseline (445.184 us; speedup 1.0000x reference)
//
#include <hip/hip_runtime.h>

// ---------------------------------------------------------------------------
// Cascade MLP, MI355X. Strategy: fp16 hi/lo split GEMMs on MFMA (3 passes,
// fp32 accum) so precision ~ fp32 while compute runs at matrix-core rate.
// Everything padded to 128 features. Transposed-output GEMM formulation:
//   D[feature][row] = W^T[feature][k] * h^T[k][row]
// so producer (C-frag regs = 4 consecutive features for one row) and consumer
// (B-frag = 4 consecutive k for one row) both traverse the feature axis ->
// LDS round trip is plain b64 writes/reads, no transpose.
// Note: half vectors are __fp16-based to match builtin prototypes (cvt_pkrtz
// returns __fp16v2; _Float16 vectors are not convertible).
// ---------------------------------------------------------------------------

typedef __fp16 h2  __attribute__((ext_vector_type(2)));
typedef __fp16 h4v __attribute__((ext_vector_type(4)));
typedef __fp16 h8v __attribute__((ext_vector_type(8)));
typedef float  f4v __attribute__((ext_vector_type(4)));

#define CHUNK 20480              // staged weight chunk (17408 used, padded for 5x16B/thread)
#define H1ROW 520                // h tile row bytes: 128 k * 4B (hi+lo interleaved per 4-k) + 8 pad
#define H1TILE 66560UL           // 128 rows * 520
#define WROW 136                 // weight chunk row bytes: 32 k * 4B + 8 pad

static constexpr size_t OFF_W1  = 0;                         // 96 chunks
static constexpr size_t OFF_WH  = 96UL * CHUNK;              // 1966080, 56 chunks
static constexpr size_t OFF_WO  = OFF_WH + 56UL * CHUNK;     // 3112960, 3 chunks
static constexpr size_t OFF_BIN = OFF_WO + 3UL * CHUNK;      // 3174400
static constexpr size_t OFF_BH  = OFF_BIN + 512;             // 3174912
static constexpr size_t OFF_BO  = OFF_BH + 14UL * 512;       // 3182080
static constexpr size_t OFF_H1  = 3182592;                   // 512 tiles * 66560

__device__ __forceinline__ unsigned bc2(h2 v) { return __builtin_bit_cast(unsigned, v); }

// split one f4v into hi(4xf16) and lo(4xf16)
__device__ __forceinline__ void split4(f4v a, h2& hi01, h2& hi23, h2& lo01, h2& lo23) {
  hi01 = __builtin_amdgcn_cvt_pkrtz(a[0], a[1]);
  hi23 = __builtin_amdgcn_cvt_pkrtz(a[2], a[3]);
  lo01 = __builtin_amdgcn_cvt_pkrtz(a[0] - (float)hi01[0], a[1] - (float)hi01[1]);
  lo23 = __builtin_amdgcn_cvt_pkrtz(a[2] - (float)hi23[0], a[3] - (float)hi23[1]);
}

__device__ __forceinline__ void lds_cp16(const char* g, char* l) {
  __builtin_amdgcn_global_load_lds(
      (const __attribute__((address_space(1))) void*)g,
      (__attribute__((address_space(3))) void*)l, 16, 0, 0);
}

// stage one CHUNK (20480B): 5 x 16B per thread, 256 threads
__device__ __forceinline__ void stage5(const char* g, char* l, int tid) {
#pragma unroll
  for (int i = 0; i < 5; ++i)
    lds_cp16(g + i * 4096 + tid * 16, l + i * 4096 + tid * 16);
}

// read one hi/lo fragment pair from LDS: layout per 4-k group = [hi 8B][lo 8B],
// k-half (+16) at +64B
__device__ __forceinline__ void rdfrag(const char* p, h8v& hi, h8v& lo) {
  h4v u0 = *(const h4v*)(p);
  h4v u1 = *(const h4v*)(p + 64);
  h4v v0 = *(const h4v*)(p + 8);
  h4v v1 = *(const h4v*)(p + 72);
  hi = __builtin_shufflevector(u0, u1, 0, 1, 2, 3, 4, 5, 6, 7);
  lo = __builtin_shufflevector(v0, v1, 0, 1, 2, 3, 4, 5, 6, 7);
}

// ---------------------------------------------------------------------------
// prep: split+pad all weights/biases into ws (runs every launch, ~3MB writes)
// ---------------------------------------------------------------------------
__global__ __launch_bounds__(256) void prep_k(
    const float* __restrict__ w_in, const float* __restrict__ b_in,
    const float* __restrict__ w_hid, const float* __restrict__ b_hid,
    const float* __restrict__ w_out, const float* __restrict__ b_out,
    char* __restrict__ ws) {
  int idx = blockIdx.x * 256 + threadIdx.x;
  float f[4];
  // W1: 96 chunks x 8 q x 128 n  (A = w_in^T rows=feature n, k padded per chunk)
  if (idx < 98304) {
    int n = idx & 127, cq = idx >> 7, q = cq & 7, c = cq >> 3;
    int k0 = c * 32 + q * 4;
#pragma unroll
    for (int j = 0; j < 4; ++j) f[j] = (n < 100) ? w_in[(size_t)(k0 + j) * 100 + n] : 0.f;
    h2 a, b, cc, d; split4(f4v{f[0], f[1], f[2], f[3]}, a, b, cc, d);
    char* dst = ws + OFF_W1 + (size_t)c * CHUNK + n * WROW + q * 16;
    *(uint2*)dst = make_uint2(bc2(a), bc2(b));
    *(uint2*)(dst + 8) = make_uint2(bc2(cc), bc2(d));
    return;
  }
  idx -= 98304;
  // WH: 56 chunks (L*4+s) x 8 q x 128 n
  if (idx < 57344) {
    int n = idx & 127, cq = idx >> 7, q = cq & 7, ch = cq >> 3;
    int L = ch >> 2, s = ch & 3;
    int k0 = s * 32 + q * 4;
#pragma unroll
    for (int j = 0; j < 4; ++j) {
      int k = k0 + j;
      f[j] = (k < 100 && n < 100) ? w_hid[(size_t)L * 10000 + k * 100 + n] : 0.f;
    }
    h2 a, b, cc, d; split4(f4v{f[0], f[1], f[2], f[3]}, a, b, cc, d);
    char* dst = ws + OFF_WH + (size_t)ch * CHUNK + n * WROW + q * 16;
    *(uint2*)dst = make_uint2(bc2(a), bc2(b));
    *(uint2*)(dst + 8) = make_uint2(bc2(cc), bc2(d));
    return;
  }
  idx -= 57344;
  // WO: 3 stages x 32 q x 16 n   (rows use H1ROW stride: k = 0..127)
  if (idx < 1536) {
    int n = idx & 15, sq = idx >> 4, q = sq & 31, st = sq >> 5;
    int k0 = q * 4;
#pragma unroll
    for (int j = 0; j < 4; ++j) {
      int k = k0 + j;
      f[j] = (k < 100 && n < 10) ? w_out[(size_t)st * 1000 + k * 10 + n] : 0.f;
    }
    h2 a, b, cc, d; split4(f4v{f[0], f[1], f[2], f[3]}, a, b, cc, d);
    char* dst = ws + OFF_WO + (size_t)st * CHUNK + n * H1ROW + q * 16;
    *(uint2*)dst = make_uint2(bc2(a), bc2(b));
    *(uint2*)(dst + 8) = make_uint2(bc2(cc), bc2(d));
    return;
  }
  idx -= 1536;
  if (idx < 128) { ((float*)(ws + OFF_BIN))[idx] = (idx < 100) ? b_in[idx] : 0.f; return; }
  idx -= 128;
  if (idx < 1792) {
    int L = idx >> 7, n = idx & 127;
    ((float*)(ws + OFF_BH))[idx] = (n < 100) ? b_hid[L * 100 + n] : 0.f;
    return;
  }
  idx -= 1792;
  if (idx < 48) {
    int st = idx >> 4, n = idx & 15;
    ((float*)(ws + OFF_BO))[idx] = (n < 10) ? b_out[st * 10 + n] : -1e30f;
    return;
  }
}

// ---------------------------------------------------------------------------
// gemm1: h1 = relu(x @ w_in + b_in), written as split-fp16 LDS-image tiles.
// 512 blocks x 256 thr (4 waves, 2x2). Wave tile = 64 features x 64 rows.
// W1 chunks: 3-buffer counted-vmcnt pipeline. x: direct HBM->reg + pkrtz split.
// ---------------------------------------------------------------------------
__global__ __launch_bounds__(256, 2) void gemm1_k(const float* __restrict__ x,
                                                  char* __restrict__ ws) {
  __shared__ __align__(16) char smA[3 * CHUNK];
  const int tid = threadIdx.x;
  const int lane = tid & 63, wid = tid >> 6;
  const int mr = wid >> 1, nc = wid & 1;
  const int l15 = lane & 15, g = lane >> 4;
  const int tile = blockIdx.x;
  const char* w1g = ws + OFF_W1;

  const float* xrow[4];
#pragma unroll
  for (int nf = 0; nf < 4; ++nf)
    xrow[nf] = x + (size_t)(tile * 128 + nc * 64 + nf * 16 + l15) * 3072;

  const int avb = (mr * 64 + l15) * WROW + g * 16;

  f4v xa[8];
  // prologue: X0 loads first, then C0, C1 (issue order matters for vmcnt(5))
#pragma unroll
  for (int nf = 0; nf < 4; ++nf) {
    xa[2 * nf] = *(const f4v*)(xrow[nf] + g * 4);
    xa[2 * nf + 1] = *(const f4v*)(xrow[nf] + g * 4 + 16);
  }
  __builtin_amdgcn_sched_barrier(0);
  stage5(w1g, smA, tid);
  stage5(w1g + CHUNK, smA + CHUNK, tid);

  f4v z = {0.f, 0.f, 0.f, 0.f};
  f4v acc[4][4] = {{z, z, z, z}, {z, z, z, z}, {z, z, z, z}, {z, z, z, z}};
  int bufc = 0;

  for (int s = 0; s < 96; ++s) {
    // wait: current x + current chunk done; next chunk (and next x) stay in flight
    if (s == 95) asm volatile("s_waitcnt vmcnt(0)" ::: "memory");
    else         asm volatile("s_waitcnt vmcnt(5)" ::: "memory");
    __builtin_amdgcn_s_barrier();
    asm volatile("" ::: "memory");

    // convert x_s -> B fragments (hi/lo)
    h8v bhi[4], blo[4];
#pragma unroll
    for (int nf = 0; nf < 4; ++nf) {
      h2 a0, a1, c0, c1, b0, b1, d0, d1;
      split4(xa[2 * nf], a0, a1, c0, c1);
      split4(xa[2 * nf + 1], b0, b1, d0, d1);
      h4v hA = __builtin_shufflevector(a0, a1, 0, 1, 2, 3);
      h4v hB = __builtin_shufflevector(b0, b1, 0, 1, 2, 3);
      h4v lA = __builtin_shufflevector(c0, c1, 0, 1, 2, 3);
      h4v lB = __builtin_shufflevector(d0, d1, 0, 1, 2, 3);
      bhi[nf] = __builtin_shufflevector(hA, hB, 0, 1, 2, 3, 4, 5, 6, 7);
      blo[nf] = __builtin_shufflevector(lA, lB, 0, 1, 2, 3, 4, 5, 6, 7);
    }
    // issue x_{s+1} (before chunk issue: keeps vmcnt FIFO accounting valid)
    if (s < 95) {
      const int k0 = (s + 1) * 32 + g * 4;
#pragma unroll
      for (int nf = 0; nf < 4; ++nf) {
        xa[2 * nf] = *(const f4v*)(xrow[nf] + k0);
        xa[2 * nf + 1] = *(const f4v*)(xrow[nf] + k0 + 16);
      }
    }
    __builtin_amdgcn_sched_barrier(0);
    if (s < 94) stage5(w1g + (size_t)(s + 2) * CHUNK, smA + ((s + 2) % 3) * CHUNK, tid);
    __builtin_amdgcn_sched_barrier(0);

    const char* ab = smA + bufc * CHUNK;
    h8v ahi[4], alo[4];
#pragma unroll
    for (int mf = 0; mf < 4; ++mf) rdfrag(ab + avb + mf * (16 * WROW), ahi[mf], alo[mf]);
#pragma unroll
    for (int mf = 0; mf < 4; ++mf)
#pragma unroll
      for (int nf = 0; nf < 4; ++nf) {
        acc[mf][nf] = __builtin_amdgcn_mfma_f32_16x16x32_f16(ahi[mf], bhi[nf], acc[mf][nf], 0, 0, 0);
        acc[mf][nf] = __builtin_amdgcn_mfma_f32_16x16x32_f16(ahi[mf], blo[nf], acc[mf][nf], 0, 0, 0);
        acc[mf][nf] = __builtin_amdgcn_mfma_f32_16x16x32_f16(alo[mf], bhi[nf], acc[mf][nf], 0, 0, 0);
      }
    bufc = (bufc == 2) ? 0 : bufc + 1;
  }

  // epilogue: bias + relu + split + store h1 tile (global image == cascade LDS image)
  const float* binp = (const float*)(ws + OFF_BIN);
  char* hbase = ws + OFF_H1 + (size_t)tile * H1TILE + (size_t)(nc * 64 + l15) * H1ROW + g * 16;
#pragma unroll
  for (int mf = 0; mf < 4; ++mf) {
    f4v bi = *(const f4v*)(binp + mr * 64 + mf * 16 + g * 4);
#pragma unroll
    for (int nf = 0; nf < 4; ++nf) {
      f4v v = acc[mf][nf] + bi;
      v[0] = fmaxf(v[0], 0.f); v[1] = fmaxf(v[1], 0.f);
      v[2] = fmaxf(v[2], 0.f); v[3] = fmaxf(v[3], 0.f);
      h2 a, b, c, d; split4(v, a, b, c, d);
      char* dst = hbase + nf * (16 * H1ROW) + mf * 64 + mr * 256;
      *(uint2*)dst = make_uint2(bc2(a), bc2(b));
      *(uint2*)(dst + 8) = make_uint2(bc2(c), bc2(d));
    }
  }
}

// ---------------------------------------------------------------------------
// cascade: 14 hidden layers + 3 heads + early-exit select. h lives in LDS,
// accumulators in registers (single h buffer). Weight chunks double-buffered,
// 1 item prefetched ahead (__syncthreads per item is fine: L2-resident weights).
// ---------------------------------------------------------------------------
#define CAS_SMEM (66560 + 2 * CHUNK)  // 107520 dynamic LDS

__global__ __launch_bounds__(256, 1) void cascade_k(char* __restrict__ ws,
                                                    float* __restrict__ out) {
  extern __shared__ __align__(16) char sm[];
  __shared__ unsigned itemOff[60];
  char* smh = sm;               // h tile, 66560
  char* smw = sm + 66560;       // 2 x CHUNK

  const int tid = threadIdx.x;
  const int lane = tid & 63, wid = tid >> 6;
  const int mr = wid >> 1, nc = wid & 1;
  const int l15 = lane & 15, g = lane >> 4;
  const int tile = blockIdx.x;

  if (tid == 0) {
    int i = 0, st = 0;
    for (int L = 0; L < 14; ++L) {
      for (int s = 0; s < 4; ++s) itemOff[i++] = (unsigned)OFF_WH + (unsigned)(L * 4 + s) * CHUNK;
      if (L == 3 || L == 8 || L == 13) itemOff[i++] = (unsigned)OFF_WO + (unsigned)(st++) * CHUNK;
    }
  }
  __syncthreads();

  {  // stage h1 tile (66560 B)
    const char* hg = ws + OFF_H1 + (size_t)tile * H1TILE;
#pragma unroll
    for (int i = 0; i < 16; ++i) lds_cp16(hg + i * 4096 + tid * 16, smh + i * 4096 + tid * 16);
    if (tid < 64) lds_cp16(hg + 65536 + tid * 16, smh + 65536 + tid * 16);
  }
  stage5(ws + itemOff[0], smw, tid);  // item 0 -> buf 0

  int item = 0;
  const int avb = (mr * 64 + l15) * WROW + g * 16;
  const int hvb = (nc * 64 + l15) * H1ROW + g * 16;
  const int wovb = l15 * H1ROW + g * 16;

  f4v z = {0.f, 0.f, 0.f, 0.f};
  f4v acc[4][4] = {{z, z, z, z}, {z, z, z, z}, {z, z, z, z}, {z, z, z, z}};
  f4v o0[4], o1[4], o2[4];
  unsigned conf = 0;

  auto item_top = [&]() {
    __syncthreads();  // drains staged item + fences LDS
    if (item < 58) stage5(ws + itemOff[item + 1], smw + ((item + 1) & 1) * CHUNK, tid);
  };

  auto hidden = [&](int L) {
#pragma unroll
    for (int s = 0; s < 4; ++s) {
      item_top();
      const char* wb = smw + (item & 1) * CHUNK;
      h8v ahi[4], alo[4], bhi[4], blo[4];
#pragma unroll
      for (int mf = 0; mf < 4; ++mf) rdfrag(wb + avb + mf * (16 * WROW), ahi[mf], alo[mf]);
#pragma unroll
      for (int nf = 0; nf < 4; ++nf) rdfrag(smh + hvb + nf * (16 * H1ROW) + s * 128, bhi[nf], blo[nf]);
#pragma unroll
      for (int mf = 0; mf < 4; ++mf)
#pragma unroll
        for (int nf = 0; nf < 4; ++nf) {
          acc[mf][nf] = __builtin_amdgcn_mfma_f32_16x16x32_f16(ahi[mf], bhi[nf], acc[mf][nf], 0, 0, 0);
          acc[mf][nf] = __builtin_amdgcn_mfma_f32_16x16x32_f16(ahi[mf], blo[nf], acc[mf][nf], 0, 0, 0);
          acc[mf][nf] = __builtin_amdgcn_mfma_f32_16x16x32_f16(alo[mf], bhi[nf], acc[mf][nf], 0, 0, 0);
        }
      ++item;
    }
    // epilogue: bias + relu + split, overwrite h in LDS
    const float* bh = (const float*)(ws + OFF_BH) + L * 128 + mr * 64 + g * 4;
    __syncthreads();  // all reads of old h done
#pragma unroll
    for (int mf = 0; mf < 4; ++mf) {
      f4v bi = *(const f4v*)(bh + mf * 16);
#pragma unroll
      for (int nf = 0; nf < 4; ++nf) {
        f4v v = acc[mf][nf] + bi;
        v[0] = fmaxf(v[0], 0.f); v[1] = fmaxf(v[1], 0.f);
        v[2] = fmaxf(v[2], 0.f); v[3] = fmaxf(v[3], 0.f);
        h2 a, b, c, d; split4(v, a, b, c, d);
        char* dst = smh + hvb + nf * (16 * H1ROW) + mf * 64 + mr * 256;
        *(uint2*)dst = make_uint2(bc2(a), bc2(b));
        *(uint2*)(dst + 8) = make_uint2(bc2(c), bc2(d));
        acc[mf][nf] = z;
      }
    }
    __syncthreads();  // new h visible
  };

  auto wstage = [&](f4v (&o)[4], int st, int shift) {
    item_top();
    const char* wb = smw + (item & 1) * CHUNK;
    if (mr == 0) {  // waves 0,1 compute the head (wave-uniform branch)
      f4v oa[4] = {z, z, z, z};
#pragma unroll
      for (int s = 0; s < 4; ++s) {
        h8v ahi, alo;
        rdfrag(wb + wovb + s * 128, ahi, alo);
#pragma unroll
        for (int nf = 0; nf < 4; ++nf) {
          h8v bhi, blo;
          rdfrag(smh + hvb + nf * (16 * H1ROW) + s * 128, bhi, blo);
          oa[nf] = __builtin_amdgcn_mfma_f32_16x16x32_f16(ahi, bhi, oa[nf], 0, 0, 0);
          oa[nf] = __builtin_amdgcn_mfma_f32_16x16x32_f16(ahi, blo, oa[nf], 0, 0, 0);
          oa[nf] = __builtin_amdgcn_mfma_f32_16x16x32_f16(alo, bhi, oa[nf], 0, 0, 0);
        }
      }
      f4v bi = *(const f4v*)((const float*)(ws + OFF_BO) + st * 16 + g * 4);
#pragma unroll
      for (int nf = 0; nf < 4; ++nf) {
        oa[nf] += bi;  // padded features carry bias -1e30 -> never win the max
        float m = fmaxf(fmaxf(oa[nf][0], oa[nf][1]), fmaxf(oa[nf][2], oa[nf][3]));
        m = fmaxf(m, __shfl_xor(m, 16, 64));
        m = fmaxf(m, __shfl_xor(m, 32, 64));
        if (m > 0.5f) conf |= 1u << (shift + nf);
        o[nf] = oa[nf];
      }
    }
    ++item;
  };

#pragma unroll 1
  for (int L = 0; L < 4; ++L) hidden(L);
  wstage(o0, 0, 0);
#pragma unroll 1
  for (int L = 4; L < 9; ++L) hidden(L);
  wstage(o1, 1, 4);
#pragma unroll 1
  for (int L = 9; L < 14; ++L) hidden(L);
  wstage(o2, 2, 8);

  if (mr == 0) {  // early-exit select + store (rows 0..127 covered by nc=0,1)
#pragma unroll
    for (int nf = 0; nf < 4; ++nf) {
      bool c0 = (conf >> nf) & 1u, c1 = (conf >> (4 + nf)) & 1u;
      f4v r;
#pragma unroll
      for (int j = 0; j < 4; ++j) r[j] = c0 ? o0[nf][j] : (c1 ? o1[nf][j] : o2[nf][j]);
      float* dp = out + (size_t)(tile * 128 + nc * 64 + nf * 16 + l15) * 10;
      if (g == 0) {
        *(float2*)(dp) = make_float2(r[0], r[1]);
        *(float2*)(dp + 2) = make_float2(r[2], r[3]);
      } else if (g == 1) {
        *(float2*)(dp + 4) = make_float2(r[0], r[1]);
        *(float2*)(dp + 6) = make_float2(r[2], r[3]);
      } else if (g == 2) {
        *(float2*)(dp + 8) = make_float2(r[0], r[1]);
      }
    }
  }
}

// ---------------------------------------------------------------------------
extern "C" void kernel_launch(void* const* d_in, const int* in_sizes, int n_in,
                              void* d_out, int out_size, void* d_ws, size_t ws_size,
                              hipStream_t stream) {
  (void)in_sizes; (void)n_in; (void)out_size; (void)ws_size;
  const float* x     = (const float*)d_in[0];
  const float* w_in  = (const float*)d_in[1];
  const float* b_in  = (const float*)d_in[2];
  const float* w_hid = (const float*)d_in[3];
  const float* b_hid = (const float*)d_in[4];
  const float* w_out = (const float*)d_in[5];
  const float* b_out = (const float*)d_in[6];
  float* out = (float*)d_out;
  char* ws = (char*)d_ws;

  // >64KB dynamic LDS opt-in (idempotent; not a stream op, capture-safe)
  (void)hipFuncSetAttribute((const void*)cascade_k,
                            hipFuncAttributeMaxDynamicSharedMemorySize, CAS_SMEM);

  prep_k<<<622, 256, 0, stream>>>(w_in, b_in, w_hid, b_hid, w_out, b_out, ws);
  gemm1_k<<<512, 256, 0, stream>>>(x, ws);
  cascade_k<<<512, 256, CAS_SMEM, stream>>>(ws, out);
}

// Round 3
// 389.241 us; speedup vs baseline: 1.1437x; 1.1437x over previous
//
#include <hip/hip_runtime.h>

// ---------------------------------------------------------------------------
// Cascade MLP, MI355X. fp16 hi/lo split GEMMs on MFMA (3 passes, fp32 accum).
// k-OCTET fragment mapping: lane (l15,g) holds k in [8g, 8g+8) for BOTH A and
// B operands (any consistent k-bijection is valid; verified by round-2 pass).
// Weight/h rows store [hi-plane][lo-plane] so one MFMA fragment == one
// ds_read_b128, no cross-lane or register shuffling anywhere.
// gemm1 + cascade fused: h lives in LDS for the whole kernel.
// ---------------------------------------------------------------------------

typedef __fp16 h2  __attribute__((ext_vector_type(2)));
typedef __fp16 h8v __attribute__((ext_vector_type(8)));
typedef float  f4v __attribute__((ext_vector_type(4)));

#define CHUNK 20480   // W chunk stride (18432 used: 128 rows x 144 B), 5x16B stage
#define WROW  144     // weight row: [hi 64B = 32k x fp16][lo 64B][pad 16B]; 144/4=36≡4 mod 32
#define HROW  528     // h row: [hi 256B = 128k][lo 256B][pad 16B]; 132≡4 mod 32
#define WOCH  12288   // head chunk stride (8448 used: 16 rows x 528 B), 3x16B stage

static constexpr unsigned OFF_W1  = 0;                       // 96 chunks
static constexpr unsigned OFF_WH  = 96u * CHUNK;             // 1966080, 56 chunks
static constexpr unsigned OFF_WO  = OFF_WH + 56u * CHUNK;    // 3112960, 3 head chunks
static constexpr unsigned OFF_BIN = OFF_WO + 3u * WOCH;      // 3149824, 128 f32
static constexpr unsigned OFF_BH  = OFF_BIN + 512;           // 3150336, 14 x 128 f32
static constexpr unsigned OFF_BO  = OFF_BH + 14u * 512;      // 3157504, 3 x 16 f32

__device__ __forceinline__ unsigned bc2(h2 v) { return __builtin_bit_cast(unsigned, v); }

__device__ __forceinline__ void lds_cp16(const char* g, char* l) {
  __builtin_amdgcn_global_load_lds(
      (const __attribute__((address_space(1))) void*)g,
      (__attribute__((address_space(3))) void*)l, 16, 0, 0);
}

// stage CHUNK bytes (5 x 16B x 256 thr) / 12288 bytes (3 x 16B x 256 thr)
__device__ __forceinline__ void stage5(const char* g, char* l, int tid) {
#pragma unroll
  for (int i = 0; i < 5; ++i) lds_cp16(g + i * 4096 + tid * 16, l + i * 4096 + tid * 16);
}
__device__ __forceinline__ void stage3(const char* g, char* l, int tid) {
#pragma unroll
  for (int i = 0; i < 3; ++i) lds_cp16(g + i * 4096 + tid * 16, l + i * 4096 + tid * 16);
}

// 8 fp32 (two f4v) -> hi/lo h8v fragments, element order [f0..f7]
__device__ __forceinline__ void cvt8(f4v a, f4v b, h8v& hi, h8v& lo) {
  h2 h0 = __builtin_amdgcn_cvt_pkrtz(a[0], a[1]);
  h2 h1 = __builtin_amdgcn_cvt_pkrtz(a[2], a[3]);
  h2 h2_ = __builtin_amdgcn_cvt_pkrtz(b[0], b[1]);
  h2 h3 = __builtin_amdgcn_cvt_pkrtz(b[2], b[3]);
  h2 l0 = __builtin_amdgcn_cvt_pkrtz(a[0] - (float)h0[0], a[1] - (float)h0[1]);
  h2 l1 = __builtin_amdgcn_cvt_pkrtz(a[2] - (float)h1[0], a[3] - (float)h1[1]);
  h2 l2 = __builtin_amdgcn_cvt_pkrtz(b[0] - (float)h2_[0], b[1] - (float)h2_[1]);
  h2 l3 = __builtin_amdgcn_cvt_pkrtz(b[2] - (float)h3[0], b[3] - (float)h3[1]);
  hi = h8v{h0[0], h0[1], h1[0], h1[1], h2_[0], h2_[1], h3[0], h3[1]};
  lo = h8v{l0[0], l0[1], l1[0], l1[1], l2[0], l2[1], l3[0], l3[1]};
}

// relu'd f4v -> 8B hi + 8B lo at the given LDS/global addresses
__device__ __forceinline__ void split_store(f4v v, char* hip, char* lop) {
  h2 a = __builtin_amdgcn_cvt_pkrtz(v[0], v[1]);
  h2 b = __builtin_amdgcn_cvt_pkrtz(v[2], v[3]);
  h2 c = __builtin_amdgcn_cvt_pkrtz(v[0] - (float)a[0], v[1] - (float)a[1]);
  h2 d = __builtin_amdgcn_cvt_pkrtz(v[2] - (float)b[0], v[3] - (float)b[1]);
  *(uint2*)hip = make_uint2(bc2(a), bc2(b));
  *(uint2*)lop = make_uint2(bc2(c), bc2(d));
}

__device__ __forceinline__ void split8w(const float* f, uint4& hi, uint4& lo) {
  h2 h0 = __builtin_amdgcn_cvt_pkrtz(f[0], f[1]);
  h2 h1 = __builtin_amdgcn_cvt_pkrtz(f[2], f[3]);
  h2 h2_ = __builtin_amdgcn_cvt_pkrtz(f[4], f[5]);
  h2 h3 = __builtin_amdgcn_cvt_pkrtz(f[6], f[7]);
  h2 l0 = __builtin_amdgcn_cvt_pkrtz(f[0] - (float)h0[0], f[1] - (float)h0[1]);
  h2 l1 = __builtin_amdgcn_cvt_pkrtz(f[2] - (float)h1[0], f[3] - (float)h1[1]);
  h2 l2 = __builtin_amdgcn_cvt_pkrtz(f[4] - (float)h2_[0], f[5] - (float)h2_[1]);
  h2 l3 = __builtin_amdgcn_cvt_pkrtz(f[6] - (float)h3[0], f[7] - (float)h3[1]);
  hi = make_uint4(bc2(h0), bc2(h1), bc2(h2_), bc2(h3));
  lo = make_uint4(bc2(l0), bc2(l1), bc2(l2), bc2(l3));
}

// item schedule: L0-3 = 0..15, head0 = 16, L4-8 = 17..36, head1 = 37,
// L9-13 = 38..57, head2 = 58  (59 items)
__device__ __forceinline__ unsigned item_off(int it) {
  if (it == 16) return OFF_WO;
  if (it == 37) return OFF_WO + WOCH;
  if (it == 58) return OFF_WO + 2u * WOCH;
  int j = it - (it > 16 ? 1 : 0) - (it > 37 ? 1 : 0);
  return OFF_WH + (unsigned)j * CHUNK;
}
__device__ __forceinline__ bool is_head(int it) { return it == 16 || it == 37 || it == 58; }

// ---------------------------------------------------------------------------
// prep: split+pad weights/biases into ws images
// ---------------------------------------------------------------------------
__global__ __launch_bounds__(256) void prep_k(
    const float* __restrict__ w_in, const float* __restrict__ b_in,
    const float* __restrict__ w_hid, const float* __restrict__ b_hid,
    const float* __restrict__ w_out, const float* __restrict__ b_out,
    char* __restrict__ ws) {
  int idx = blockIdx.x * 256 + threadIdx.x;
  float f[8];
  uint4 hi, lo;
  // W1: c(96) x q(4) x n(128); k = c*32 + q*8 + j
  if (idx < 49152) {
    int n = idx & 127, cq = idx >> 7, q = cq & 3, c = cq >> 2;
    int k0 = c * 32 + q * 8;
#pragma unroll
    for (int j = 0; j < 8; ++j) f[j] = (n < 100) ? w_in[(size_t)(k0 + j) * 100 + n] : 0.f;
    split8w(f, hi, lo);
    char* dst = ws + OFF_W1 + (size_t)c * CHUNK + n * WROW + q * 16;
    *(uint4*)dst = hi;
    *(uint4*)(dst + 64) = lo;
    return;
  }
  idx -= 49152;
  // WH: ch(56 = L*4+s) x q(4) x n(128); k = s*32 + q*8 + j
  if (idx < 28672) {
    int n = idx & 127, cq = idx >> 7, q = cq & 3, ch = cq >> 2;
    int L = ch >> 2, s = ch & 3;
    int k0 = s * 32 + q * 8;
#pragma unroll
    for (int j = 0; j < 8; ++j) {
      int k = k0 + j;
      f[j] = (k < 100 && n < 100) ? w_hid[(size_t)L * 10000 + k * 100 + n] : 0.f;
    }
    split8w(f, hi, lo);
    char* dst = ws + OFF_WH + (size_t)ch * CHUNK + n * WROW + q * 16;
    *(uint4*)dst = hi;
    *(uint4*)(dst + 64) = lo;
    return;
  }
  idx -= 28672;
  // WO: st(3) x q(16) x l(16); rows are HROW with full 128-k planes
  if (idx < 768) {
    int l = idx & 15, sq = idx >> 4, q = sq & 15, st = sq >> 4;
    int k0 = q * 8;
#pragma unroll
    for (int j = 0; j < 8; ++j) {
      int k = k0 + j;
      f[j] = (k < 100 && l < 10) ? w_out[(size_t)st * 1000 + k * 10 + l] : 0.f;
    }
    split8w(f, hi, lo);
    char* dst = ws + OFF_WO + (size_t)st * WOCH + l * HROW + q * 16;
    *(uint4*)dst = hi;
    *(uint4*)(dst + 256) = lo;
    return;
  }
  idx -= 768;
  if (idx < 128) { ((float*)(ws + OFF_BIN))[idx] = (idx < 100) ? b_in[idx] : 0.f; return; }
  idx -= 128;
  if (idx < 1792) {
    int L = idx >> 7, n = idx & 127;
    ((float*)(ws + OFF_BH))[idx] = (n < 100) ? b_hid[L * 100 + n] : 0.f;
    return;
  }
  idx -= 1792;
  if (idx < 48) {
    int st = idx >> 4, n = idx & 15;
    ((float*)(ws + OFF_BO))[idx] = (n < 10) ? b_out[st * 10 + n] : -1e30f;
    return;
  }
}

// ---------------------------------------------------------------------------
// fused: phase 1 (x @ w_in, HBM-bound) writes h into LDS; phase 2 runs the
// 14-layer cascade + 3 heads + early-exit select from LDS.
// ---------------------------------------------------------------------------
#define SMEM_BYTES (128 * HROW + 3 * CHUNK)  // 67584 + 61440 = 129024

__global__ __launch_bounds__(256, 1) void fused_k(const float* __restrict__ x,
                                                  char* __restrict__ ws,
                                                  float* __restrict__ out) {
  extern __shared__ __align__(16) char sm[];
  char* smh = sm;                 // h tile: 128 rows x HROW
  char* smw = sm + 128 * HROW;    // 3 x CHUNK staging buffers

  const int tid = threadIdx.x;
  const int lane = tid & 63, wid = tid >> 6;
  const int l15 = lane & 15, g = lane >> 4;
  const int tile = blockIdx.x;

  // ================= phase 1: h1 = relu(x @ w_in + b_in) =================
  {
    const char* w1g = ws + OFF_W1;
    const float* xr0 = x + (size_t)(tile * 128 + wid * 32 + l15) * 3072;
    const float* xr1 = xr0 + (size_t)16 * 3072;

    f4v xaP[4], xaQ[4];
    // prologue FIFO: c0(5), x0(4), c1(5), x1(4)
    stage5(w1g, smw, tid);
    __builtin_amdgcn_sched_barrier(0);
    xaP[0] = *(const f4v*)(xr0 + g * 8); xaP[1] = *(const f4v*)(xr0 + g * 8 + 4);
    xaP[2] = *(const f4v*)(xr1 + g * 8); xaP[3] = *(const f4v*)(xr1 + g * 8 + 4);
    __builtin_amdgcn_sched_barrier(0);
    stage5(w1g + CHUNK, smw + CHUNK, tid);
    __builtin_amdgcn_sched_barrier(0);
    {
      const int o = 32 + g * 8;
      xaQ[0] = *(const f4v*)(xr0 + o); xaQ[1] = *(const f4v*)(xr0 + o + 4);
      xaQ[2] = *(const f4v*)(xr1 + o); xaQ[3] = *(const f4v*)(xr1 + o + 4);
    }
    __builtin_amdgcn_sched_barrier(0);

    f4v z = {0.f, 0.f, 0.f, 0.f};
    f4v acc[8][2];
#pragma unroll
    for (int mf = 0; mf < 8; ++mf) { acc[mf][0] = z; acc[mf][1] = z; }

    const int abase = l15 * WROW + g * 16;

    auto step = [&](int s, f4v (&xa)[4]) {
      if (s == 95) asm volatile("s_waitcnt vmcnt(0)" ::: "memory");
      else         asm volatile("s_waitcnt vmcnt(9)" ::: "memory");
      __builtin_amdgcn_s_barrier();
      asm volatile("" ::: "memory");

      h8v bhi0, blo0, bhi1, blo1;
      cvt8(xa[0], xa[1], bhi0, blo0);
      cvt8(xa[2], xa[3], bhi1, blo1);
      // refill: stage c(s+2) then x(s+2) (9 VMEM issues per step total)
      if (s + 2 < 96) {
        stage5(w1g + (size_t)(s + 2) * CHUNK, smw + ((s + 2) % 3) * CHUNK, tid);
        const int o = (s + 2) * 32 + g * 8;
        xa[0] = *(const f4v*)(xr0 + o); xa[1] = *(const f4v*)(xr0 + o + 4);
        xa[2] = *(const f4v*)(xr1 + o); xa[3] = *(const f4v*)(xr1 + o + 4);
      }
      __builtin_amdgcn_sched_barrier(0);

      const char* ab = smw + (s % 3) * CHUNK + abase;
#pragma unroll
      for (int mf = 0; mf < 8; ++mf) {
        h8v ahi = *(const h8v*)(ab + mf * (16 * WROW));
        h8v alo = *(const h8v*)(ab + mf * (16 * WROW) + 64);
        acc[mf][0] = __builtin_amdgcn_mfma_f32_16x16x32_f16(ahi, bhi0, acc[mf][0], 0, 0, 0);
        acc[mf][0] = __builtin_amdgcn_mfma_f32_16x16x32_f16(ahi, blo0, acc[mf][0], 0, 0, 0);
        acc[mf][0] = __builtin_amdgcn_mfma_f32_16x16x32_f16(alo, bhi0, acc[mf][0], 0, 0, 0);
        acc[mf][1] = __builtin_amdgcn_mfma_f32_16x16x32_f16(ahi, bhi1, acc[mf][1], 0, 0, 0);
        acc[mf][1] = __builtin_amdgcn_mfma_f32_16x16x32_f16(ahi, blo1, acc[mf][1], 0, 0, 0);
        acc[mf][1] = __builtin_amdgcn_mfma_f32_16x16x32_f16(alo, bhi1, acc[mf][1], 0, 0, 0);
      }
    };

#pragma unroll 1
    for (int s2 = 0; s2 < 96; s2 += 2) {
      step(s2, xaP);
      step(s2 + 1, xaQ);
    }

    // epilogue: bias + relu + split -> h rows; pre-stage phase-2 items 0,1
    stage5(ws + item_off(0), smw, tid);
    stage5(ws + item_off(1), smw + CHUNK, tid);
    const float* binp = (const float*)(ws + OFF_BIN);
#pragma unroll
    for (int nf = 0; nf < 2; ++nf) {
      char* hrow = smh + (wid * 32 + nf * 16 + l15) * HROW;
#pragma unroll
      for (int mf = 0; mf < 8; ++mf) {
        f4v bi = *(const f4v*)(binp + mf * 16 + g * 4);
        f4v v = acc[mf][nf] + bi;
        v[0] = fmaxf(v[0], 0.f); v[1] = fmaxf(v[1], 0.f);
        v[2] = fmaxf(v[2], 0.f); v[3] = fmaxf(v[3], 0.f);
        split_store(v, hrow + mf * 32 + g * 8, hrow + 256 + mf * 32 + g * 8);
      }
    }
    __syncthreads();
  }

  // ================= phase 2: cascade =================
  const int mr = wid >> 1, nc = wid & 1;
  f4v z = {0.f, 0.f, 0.f, 0.f};
  f4v acc[4][4] = {{z, z, z, z}, {z, z, z, z}, {z, z, z, z}, {z, z, z, z}};
  f4v o0[4], o1[4], o2[4];
  unsigned conf = 0;
  int item = 0;

  auto item_top = [&]() {
    __syncthreads();
    if (item + 2 < 59) {
      unsigned off = item_off(item + 2);
      char* buf = smw + ((item + 2) % 3) * CHUNK;
      if (is_head(item + 2)) stage3(ws + off, buf, tid);
      else                   stage5(ws + off, buf, tid);
    }
  };

  auto hidden = [&](int L) {
#pragma unroll
    for (int ss = 0; ss < 4; ++ss) {
      item_top();
      const char* wb = smw + (item % 3) * CHUNK + g * 16;
      const char* hb = smh + ss * 64 + g * 16;
      h8v bhi[4], blo[4];
#pragma unroll
      for (int nf = 0; nf < 4; ++nf) {
        const char* p = hb + (nc * 64 + nf * 16 + l15) * HROW;
        bhi[nf] = *(const h8v*)p;
        blo[nf] = *(const h8v*)(p + 256);
      }
#pragma unroll
      for (int mf = 0; mf < 4; ++mf) {
        const char* pa = wb + (mr * 64 + mf * 16 + l15) * WROW;
        h8v ahi = *(const h8v*)pa;
        h8v alo = *(const h8v*)(pa + 64);
#pragma unroll
        for (int nf = 0; nf < 4; ++nf) {
          acc[mf][nf] = __builtin_amdgcn_mfma_f32_16x16x32_f16(ahi, bhi[nf], acc[mf][nf], 0, 0, 0);
          acc[mf][nf] = __builtin_amdgcn_mfma_f32_16x16x32_f16(ahi, blo[nf], acc[mf][nf], 0, 0, 0);
          acc[mf][nf] = __builtin_amdgcn_mfma_f32_16x16x32_f16(alo, bhi[nf], acc[mf][nf], 0, 0, 0);
        }
      }
      ++item;
    }
    const float* bh = (const float*)(ws + OFF_BH) + L * 128 + mr * 64;
    __syncthreads();  // all reads of old h done
#pragma unroll
    for (int mf = 0; mf < 4; ++mf) {
      f4v bi = *(const f4v*)(bh + mf * 16 + g * 4);
#pragma unroll
      for (int nf = 0; nf < 4; ++nf) {
        f4v v = acc[mf][nf] + bi;
        v[0] = fmaxf(v[0], 0.f); v[1] = fmaxf(v[1], 0.f);
        v[2] = fmaxf(v[2], 0.f); v[3] = fmaxf(v[3], 0.f);
        char* hrow = smh + (nc * 64 + nf * 16 + l15) * HROW;
        split_store(v, hrow + mr * 128 + mf * 32 + g * 8,
                    hrow + 256 + mr * 128 + mf * 32 + g * 8);
        acc[mf][nf] = z;
      }
    }
    __syncthreads();  // new h visible
  };

  auto wstage = [&](f4v (&o)[4], int st, int shift) {
    item_top();
    const char* wb = smw + (item % 3) * CHUNK;
    if (mr == 0) {  // waves 0,1: wave-uniform branch
      f4v oa[4] = {z, z, z, z};
#pragma unroll
      for (int ss = 0; ss < 4; ++ss) {
        const char* pa = wb + l15 * HROW + ss * 64 + g * 16;
        h8v ahi = *(const h8v*)pa;
        h8v alo = *(const h8v*)(pa + 256);
#pragma unroll
        for (int nf = 0; nf < 4; ++nf) {
          const char* pb = smh + (nc * 64 + nf * 16 + l15) * HROW + ss * 64 + g * 16;
          h8v bhi = *(const h8v*)pb;
          h8v blo = *(const h8v*)(pb + 256);
          oa[nf] = __builtin_amdgcn_mfma_f32_16x16x32_f16(ahi, bhi, oa[nf], 0, 0, 0);
          oa[nf] = __builtin_amdgcn_mfma_f32_16x16x32_f16(ahi, blo, oa[nf], 0, 0, 0);
          oa[nf] = __builtin_amdgcn_mfma_f32_16x16x32_f16(alo, bhi, oa[nf], 0, 0, 0);
        }
      }
      f4v bi = *(const f4v*)((const float*)(ws + OFF_BO) + st * 16 + g * 4);
#pragma unroll
      for (int nf = 0; nf < 4; ++nf) {
        oa[nf] += bi;  // padded classes carry bias -1e30
        float m = fmaxf(fmaxf(oa[nf][0], oa[nf][1]), fmaxf(oa[nf][2], oa[nf][3]));
        m = fmaxf(m, __shfl_xor(m, 16, 64));
        m = fmaxf(m, __shfl_xor(m, 32, 64));
        if (m > 0.5f) conf |= 1u << (shift + nf);
        o[nf] = oa[nf];
      }
    }
    ++item;
  };

#pragma unroll 1
  for (int L = 0; L < 4; ++L) hidden(L);
  wstage(o0, 0, 0);
#pragma unroll 1
  for (int L = 4; L < 9; ++L) hidden(L);
  wstage(o1, 1, 4);
#pragma unroll 1
  for (int L = 9; L < 14; ++L) hidden(L);
  wstage(o2, 2, 8);

  if (mr == 0) {  // early-exit select + store
#pragma unroll
    for (int nf = 0; nf < 4; ++nf) {
      bool c0 = (conf >> nf) & 1u, c1 = (conf >> (4 + nf)) & 1u;
      f4v r;
#pragma unroll
      for (int j = 0; j < 4; ++j) r[j] = c0 ? o0[nf][j] : (c1 ? o1[nf][j] : o2[nf][j]);
      float* dp = out + (size_t)(tile * 128 + nc * 64 + nf * 16 + l15) * 10;
      if (g == 0) {
        *(float2*)(dp) = make_float2(r[0], r[1]);
        *(float2*)(dp + 2) = make_float2(r[2], r[3]);
      } else if (g == 1) {
        *(float2*)(dp + 4) = make_float2(r[0], r[1]);
        *(float2*)(dp + 6) = make_float2(r[2], r[3]);
      } else if (g == 2) {
        *(float2*)(dp + 8) = make_float2(r[0], r[1]);
      }
    }
  }
}

// ---------------------------------------------------------------------------
extern "C" void kernel_launch(void* const* d_in, const int* in_sizes, int n_in,
                              void* d_out, int out_size, void* d_ws, size_t ws_size,
                              hipStream_t stream) {
  (void)in_sizes; (void)n_in; (void)out_size; (void)ws_size;
  const float* x     = (const float*)d_in[0];
  const float* w_in  = (const float*)d_in[1];
  const float* b_in  = (const float*)d_in[2];
  const float* w_hid = (const float*)d_in[3];
  const float* b_hid = (const float*)d_in[4];
  const float* w_out = (const float*)d_in[5];
  const float* b_out = (const float*)d_in[6];
  float* out = (float*)d_out;
  char* ws = (char*)d_ws;

  (void)hipFuncSetAttribute((const void*)fused_k,
                            hipFuncAttributeMaxDynamicSharedMemorySize, SMEM_BYTES);

  prep_k<<<315, 256, 0, stream>>>(w_in, b_in, w_hid, b_hid, w_out, b_out, ws);
  fused_k<<<512, 256, SMEM_BYTES, stream>>>(x, ws, out);
}

// Round 4
// 382.981 us; speedup vs baseline: 1.1624x; 1.0163x over previous
//
#include <hip/hip_runtime.h>

// ---------------------------------------------------------------------------
// Cascade MLP, MI355X. fp16 hi/lo split GEMMs on MFMA (3 passes, fp32 accum).
// k-OCTET fragment mapping: lane (l15,g) holds k in [8g, 8g+8) for BOTH A and
// B operands. Weight/h rows store [hi-plane][lo-plane] so one MFMA fragment ==
// one ds_read_b128. gemm1 + cascade fused: h lives in LDS for the whole kernel.
// Round-4 change: x loads are NON-TEMPORAL (read-once stream) so the shared
// weight images stay L2-resident instead of being thrashed by the x stream.
// ---------------------------------------------------------------------------

typedef __fp16 h2  __attribute__((ext_vector_type(2)));
typedef __fp16 h8v __attribute__((ext_vector_type(8)));
typedef float  f4v __attribute__((ext_vector_type(4)));

#define CHUNK 20480   // W chunk stride (18432 used: 128 rows x 144 B), 5x16B stage
#define WROW  144     // weight row: [hi 64B = 32k x fp16][lo 64B][pad 16B]; 36≡4 mod 32
#define HROW  528     // h row: [hi 256B = 128k][lo 256B][pad 16B]; 132≡4 mod 32
#define WOCH  12288   // head chunk stride (8448 used: 16 rows x 528 B), 3x16B stage

static constexpr unsigned OFF_W1  = 0;                       // 96 chunks
static constexpr unsigned OFF_WH  = 96u * CHUNK;             // 1966080, 56 chunks
static constexpr unsigned OFF_WO  = OFF_WH + 56u * CHUNK;    // 3112960, 3 head chunks
static constexpr unsigned OFF_BIN = OFF_WO + 3u * WOCH;      // 3149824, 128 f32
static constexpr unsigned OFF_BH  = OFF_BIN + 512;           // 3150336, 14 x 128 f32
static constexpr unsigned OFF_BO  = OFF_BH + 14u * 512;      // 3157504, 3 x 16 f32

__device__ __forceinline__ unsigned bc2(h2 v) { return __builtin_bit_cast(unsigned, v); }

__device__ __forceinline__ f4v ntld4(const float* p) {
  return __builtin_nontemporal_load((const f4v*)p);
}

__device__ __forceinline__ void lds_cp16(const char* g, char* l) {
  __builtin_amdgcn_global_load_lds(
      (const __attribute__((address_space(1))) void*)g,
      (__attribute__((address_space(3))) void*)l, 16, 0, 0);
}

__device__ __forceinline__ void stage5(const char* g, char* l, int tid) {
#pragma unroll
  for (int i = 0; i < 5; ++i) lds_cp16(g + i * 4096 + tid * 16, l + i * 4096 + tid * 16);
}
__device__ __forceinline__ void stage3(const char* g, char* l, int tid) {
#pragma unroll
  for (int i = 0; i < 3; ++i) lds_cp16(g + i * 4096 + tid * 16, l + i * 4096 + tid * 16);
}

// 8 fp32 (two f4v) -> hi/lo h8v fragments, element order [f0..f7]
__device__ __forceinline__ void cvt8(f4v a, f4v b, h8v& hi, h8v& lo) {
  h2 h0 = __builtin_amdgcn_cvt_pkrtz(a[0], a[1]);
  h2 h1 = __builtin_amdgcn_cvt_pkrtz(a[2], a[3]);
  h2 h2_ = __builtin_amdgcn_cvt_pkrtz(b[0], b[1]);
  h2 h3 = __builtin_amdgcn_cvt_pkrtz(b[2], b[3]);
  h2 l0 = __builtin_amdgcn_cvt_pkrtz(a[0] - (float)h0[0], a[1] - (float)h0[1]);
  h2 l1 = __builtin_amdgcn_cvt_pkrtz(a[2] - (float)h1[0], a[3] - (float)h1[1]);
  h2 l2 = __builtin_amdgcn_cvt_pkrtz(b[0] - (float)h2_[0], b[1] - (float)h2_[1]);
  h2 l3 = __builtin_amdgcn_cvt_pkrtz(b[2] - (float)h3[0], b[3] - (float)h3[1]);
  hi = h8v{h0[0], h0[1], h1[0], h1[1], h2_[0], h2_[1], h3[0], h3[1]};
  lo = h8v{l0[0], l0[1], l1[0], l1[1], l2[0], l2[1], l3[0], l3[1]};
}

// relu'd f4v -> 8B hi + 8B lo
__device__ __forceinline__ void split_store(f4v v, char* hip, char* lop) {
  h2 a = __builtin_amdgcn_cvt_pkrtz(v[0], v[1]);
  h2 b = __builtin_amdgcn_cvt_pkrtz(v[2], v[3]);
  h2 c = __builtin_amdgcn_cvt_pkrtz(v[0] - (float)a[0], v[1] - (float)a[1]);
  h2 d = __builtin_amdgcn_cvt_pkrtz(v[2] - (float)b[0], v[3] - (float)b[1]);
  *(uint2*)hip = make_uint2(bc2(a), bc2(b));
  *(uint2*)lop = make_uint2(bc2(c), bc2(d));
}

__device__ __forceinline__ void split8w(const float* f, uint4& hi, uint4& lo) {
  h2 h0 = __builtin_amdgcn_cvt_pkrtz(f[0], f[1]);
  h2 h1 = __builtin_amdgcn_cvt_pkrtz(f[2], f[3]);
  h2 h2_ = __builtin_amdgcn_cvt_pkrtz(f[4], f[5]);
  h2 h3 = __builtin_amdgcn_cvt_pkrtz(f[6], f[7]);
  h2 l0 = __builtin_amdgcn_cvt_pkrtz(f[0] - (float)h0[0], f[1] - (float)h0[1]);
  h2 l1 = __builtin_amdgcn_cvt_pkrtz(f[2] - (float)h1[0], f[3] - (float)h1[1]);
  h2 l2 = __builtin_amdgcn_cvt_pkrtz(f[4] - (float)h2_[0], f[5] - (float)h2_[1]);
  h2 l3 = __builtin_amdgcn_cvt_pkrtz(f[6] - (float)h3[0], f[7] - (float)h3[1]);
  hi = make_uint4(bc2(h0), bc2(h1), bc2(h2_), bc2(h3));
  lo = make_uint4(bc2(l0), bc2(l1), bc2(l2), bc2(l3));
}

// item schedule: L0-3 = 0..15, head0 = 16, L4-8 = 17..36, head1 = 37,
// L9-13 = 38..57, head2 = 58  (59 items)
__device__ __forceinline__ unsigned item_off(int it) {
  if (it == 16) return OFF_WO;
  if (it == 37) return OFF_WO + WOCH;
  if (it == 58) return OFF_WO + 2u * WOCH;
  int j = it - (it > 16 ? 1 : 0) - (it > 37 ? 1 : 0);
  return OFF_WH + (unsigned)j * CHUNK;
}
__device__ __forceinline__ bool is_head(int it) { return it == 16 || it == 37 || it == 58; }

// ---------------------------------------------------------------------------
// prep: split+pad weights/biases into ws images
// ---------------------------------------------------------------------------
__global__ __launch_bounds__(256) void prep_k(
    const float* __restrict__ w_in, const float* __restrict__ b_in,
    const float* __restrict__ w_hid, const float* __restrict__ b_hid,
    const float* __restrict__ w_out, const float* __restrict__ b_out,
    char* __restrict__ ws) {
  int idx = blockIdx.x * 256 + threadIdx.x;
  float f[8];
  uint4 hi, lo;
  if (idx < 49152) {  // W1: c(96) x q(4) x n(128); k = c*32 + q*8 + j
    int n = idx & 127, cq = idx >> 7, q = cq & 3, c = cq >> 2;
    int k0 = c * 32 + q * 8;
#pragma unroll
    for (int j = 0; j < 8; ++j) f[j] = (n < 100) ? w_in[(size_t)(k0 + j) * 100 + n] : 0.f;
    split8w(f, hi, lo);
    char* dst = ws + OFF_W1 + (size_t)c * CHUNK + n * WROW + q * 16;
    *(uint4*)dst = hi;
    *(uint4*)(dst + 64) = lo;
    return;
  }
  idx -= 49152;
  if (idx < 28672) {  // WH: ch(56 = L*4+s) x q(4) x n(128); k = s*32 + q*8 + j
    int n = idx & 127, cq = idx >> 7, q = cq & 3, ch = cq >> 2;
    int L = ch >> 2, s = ch & 3;
    int k0 = s * 32 + q * 8;
#pragma unroll
    for (int j = 0; j < 8; ++j) {
      int k = k0 + j;
      f[j] = (k < 100 && n < 100) ? w_hid[(size_t)L * 10000 + k * 100 + n] : 0.f;
    }
    split8w(f, hi, lo);
    char* dst = ws + OFF_WH + (size_t)ch * CHUNK + n * WROW + q * 16;
    *(uint4*)dst = hi;
    *(uint4*)(dst + 64) = lo;
    return;
  }
  idx -= 28672;
  if (idx < 768) {  // WO: st(3) x q(16) x l(16); rows are HROW, full 128-k planes
    int l = idx & 15, sq = idx >> 4, q = sq & 15, st = sq >> 4;
    int k0 = q * 8;
#pragma unroll
    for (int j = 0; j < 8; ++j) {
      int k = k0 + j;
      f[j] = (k < 100 && l < 10) ? w_out[(size_t)st * 1000 + k * 10 + l] : 0.f;
    }
    split8w(f, hi, lo);
    char* dst = ws + OFF_WO + (size_t)st * WOCH + l * HROW + q * 16;
    *(uint4*)dst = hi;
    *(uint4*)(dst + 256) = lo;
    return;
  }
  idx -= 768;
  if (idx < 128) { ((float*)(ws + OFF_BIN))[idx] = (idx < 100) ? b_in[idx] : 0.f; return; }
  idx -= 128;
  if (idx < 1792) {
    int L = idx >> 7, n = idx & 127;
    ((float*)(ws + OFF_BH))[idx] = (n < 100) ? b_hid[L * 100 + n] : 0.f;
    return;
  }
  idx -= 1792;
  if (idx < 48) {
    int st = idx >> 4, n = idx & 15;
    ((float*)(ws + OFF_BO))[idx] = (n < 10) ? b_out[st * 10 + n] : -1e30f;
    return;
  }
}

// ---------------------------------------------------------------------------
// fused: phase 1 (x @ w_in, HBM-bound) writes h into LDS; phase 2 runs the
// 14-layer cascade + 3 heads + early-exit select from LDS.
// ---------------------------------------------------------------------------
#define SMEM_BYTES (128 * HROW + 3 * CHUNK)  // 67584 + 61440 = 129024

__global__ __launch_bounds__(256, 1) void fused_k(const float* __restrict__ x,
                                                  char* __restrict__ ws,
                                                  float* __restrict__ out) {
  extern __shared__ __align__(16) char sm[];
  char* smh = sm;                 // h tile: 128 rows x HROW
  char* smw = sm + 128 * HROW;    // 3 x CHUNK staging buffers

  const int tid = threadIdx.x;
  const int lane = tid & 63, wid = tid >> 6;
  const int l15 = lane & 15, g = lane >> 4;
  const int tile = blockIdx.x;

  // ================= phase 1: h1 = relu(x @ w_in + b_in) =================
  {
    const char* w1g = ws + OFF_W1;
    const float* xr0 = x + (size_t)(tile * 128 + wid * 32 + l15) * 3072;
    const float* xr1 = xr0 + (size_t)16 * 3072;

    f4v xaP[4], xaQ[4];
    // prologue FIFO: c0(5), x0(4), c1(5), x1(4)
    stage5(w1g, smw, tid);
    __builtin_amdgcn_sched_barrier(0);
    xaP[0] = ntld4(xr0 + g * 8); xaP[1] = ntld4(xr0 + g * 8 + 4);
    xaP[2] = ntld4(xr1 + g * 8); xaP[3] = ntld4(xr1 + g * 8 + 4);
    __builtin_amdgcn_sched_barrier(0);
    stage5(w1g + CHUNK, smw + CHUNK, tid);
    __builtin_amdgcn_sched_barrier(0);
    {
      const int o = 32 + g * 8;
      xaQ[0] = ntld4(xr0 + o); xaQ[1] = ntld4(xr0 + o + 4);
      xaQ[2] = ntld4(xr1 + o); xaQ[3] = ntld4(xr1 + o + 4);
    }
    __builtin_amdgcn_sched_barrier(0);

    f4v z = {0.f, 0.f, 0.f, 0.f};
    f4v acc[8][2];
#pragma unroll
    for (int mf = 0; mf < 8; ++mf) { acc[mf][0] = z; acc[mf][1] = z; }

    const int abase = l15 * WROW + g * 16;

    auto step = [&](int s, f4v (&xa)[4]) {
      if (s == 95) asm volatile("s_waitcnt vmcnt(0)" ::: "memory");
      else         asm volatile("s_waitcnt vmcnt(9)" ::: "memory");
      __builtin_amdgcn_s_barrier();
      asm volatile("" ::: "memory");

      h8v bhi0, blo0, bhi1, blo1;
      cvt8(xa[0], xa[1], bhi0, blo0);
      cvt8(xa[2], xa[3], bhi1, blo1);
      // refill: stage c(s+2) then x(s+2) (9 VMEM issues per step total)
      if (s + 2 < 96) {
        stage5(w1g + (size_t)(s + 2) * CHUNK, smw + ((s + 2) % 3) * CHUNK, tid);
        const int o = (s + 2) * 32 + g * 8;
        xa[0] = ntld4(xr0 + o); xa[1] = ntld4(xr0 + o + 4);
        xa[2] = ntld4(xr1 + o); xa[3] = ntld4(xr1 + o + 4);
      }
      __builtin_amdgcn_sched_barrier(0);

      const char* ab = smw + (s % 3) * CHUNK + abase;
#pragma unroll
      for (int mf = 0; mf < 8; ++mf) {
        h8v ahi = *(const h8v*)(ab + mf * (16 * WROW));
        h8v alo = *(const h8v*)(ab + mf * (16 * WROW) + 64);
        acc[mf][0] = __builtin_amdgcn_mfma_f32_16x16x32_f16(ahi, bhi0, acc[mf][0], 0, 0, 0);
        acc[mf][0] = __builtin_amdgcn_mfma_f32_16x16x32_f16(ahi, blo0, acc[mf][0], 0, 0, 0);
        acc[mf][0] = __builtin_amdgcn_mfma_f32_16x16x32_f16(alo, bhi0, acc[mf][0], 0, 0, 0);
        acc[mf][1] = __builtin_amdgcn_mfma_f32_16x16x32_f16(ahi, bhi1, acc[mf][1], 0, 0, 0);
        acc[mf][1] = __builtin_amdgcn_mfma_f32_16x16x32_f16(ahi, blo1, acc[mf][1], 0, 0, 0);
        acc[mf][1] = __builtin_amdgcn_mfma_f32_16x16x32_f16(alo, bhi1, acc[mf][1], 0, 0, 0);
      }
    };

#pragma unroll 1
    for (int s2 = 0; s2 < 96; s2 += 2) {
      step(s2, xaP);
      step(s2 + 1, xaQ);
    }

    // epilogue: bias + relu + split -> h rows; pre-stage phase-2 items 0,1
    stage5(ws + item_off(0), smw, tid);
    stage5(ws + item_off(1), smw + CHUNK, tid);
    const float* binp = (const float*)(ws + OFF_BIN);
#pragma unroll
    for (int nf = 0; nf < 2; ++nf) {
      char* hrow = smh + (wid * 32 + nf * 16 + l15) * HROW;
#pragma unroll
      for (int mf = 0; mf < 8; ++mf) {
        f4v bi = *(const f4v*)(binp + mf * 16 + g * 4);
        f4v v = acc[mf][nf] + bi;
        v[0] = fmaxf(v[0], 0.f); v[1] = fmaxf(v[1], 0.f);
        v[2] = fmaxf(v[2], 0.f); v[3] = fmaxf(v[3], 0.f);
        split_store(v, hrow + mf * 32 + g * 8, hrow + 256 + mf * 32 + g * 8);
      }
    }
    __syncthreads();
  }

  // ================= phase 2: cascade =================
  const int mr = wid >> 1, nc = wid & 1;
  f4v z = {0.f, 0.f, 0.f, 0.f};
  f4v acc[4][4] = {{z, z, z, z}, {z, z, z, z}, {z, z, z, z}, {z, z, z, z}};
  f4v o0[4], o1[4], o2[4];
  unsigned conf = 0;
  int item = 0;

  auto item_top = [&]() {
    __syncthreads();
    if (item + 2 < 59) {
      unsigned off = item_off(item + 2);
      char* buf = smw + ((item + 2) % 3) * CHUNK;
      if (is_head(item + 2)) stage3(ws + off, buf, tid);
      else                   stage5(ws + off, buf, tid);
    }
  };

  auto hidden = [&](int L) {
#pragma unroll
    for (int ss = 0; ss < 4; ++ss) {
      item_top();
      const char* wb = smw + (item % 3) * CHUNK + g * 16;
      const char* hb = smh + ss * 64 + g * 16;
      h8v bhi[4], blo[4];
#pragma unroll
      for (int nf = 0; nf < 4; ++nf) {
        const char* p = hb + (nc * 64 + nf * 16 + l15) * HROW;
        bhi[nf] = *(const h8v*)p;
        blo[nf] = *(const h8v*)(p + 256);
      }
#pragma unroll
      for (int mf = 0; mf < 4; ++mf) {
        const char* pa = wb + (mr * 64 + mf * 16 + l15) * WROW;
        h8v ahi = *(const h8v*)pa;
        h8v alo = *(const h8v*)(pa + 64);
#pragma unroll
        for (int nf = 0; nf < 4; ++nf) {
          acc[mf][nf] = __builtin_amdgcn_mfma_f32_16x16x32_f16(ahi, bhi[nf], acc[mf][nf], 0, 0, 0);
          acc[mf][nf] = __builtin_amdgcn_mfma_f32_16x16x32_f16(ahi, blo[nf], acc[mf][nf], 0, 0, 0);
          acc[mf][nf] = __builtin_amdgcn_mfma_f32_16x16x32_f16(alo, bhi[nf], acc[mf][nf], 0, 0, 0);
        }
      }
      ++item;
    }
    const float* bh = (const float*)(ws + OFF_BH) + L * 128 + mr * 64;
    __syncthreads();  // all reads of old h done
#pragma unroll
    for (int mf = 0; mf < 4; ++mf) {
      f4v bi = *(const f4v*)(bh + mf * 16 + g * 4);
#pragma unroll
      for (int nf = 0; nf < 4; ++nf) {
        f4v v = acc[mf][nf] + bi;
        v[0] = fmaxf(v[0], 0.f); v[1] = fmaxf(v[1], 0.f);
        v[2] = fmaxf(v[2], 0.f); v[3] = fmaxf(v[3], 0.f);
        char* hrow = smh + (nc * 64 + nf * 16 + l15) * HROW;
        split_store(v, hrow + mr * 128 + mf * 32 + g * 8,
                    hrow + 256 + mr * 128 + mf * 32 + g * 8);
        acc[mf][nf] = z;
      }
    }
    __syncthreads();  // new h visible
  };

  auto wstage = [&](f4v (&o)[4], int st, int shift) {
    item_top();
    const char* wb = smw + (item % 3) * CHUNK;
    if (mr == 0) {  // waves 0,1: wave-uniform branch
      f4v oa[4] = {z, z, z, z};
#pragma unroll
      for (int ss = 0; ss < 4; ++ss) {
        const char* pa = wb + l15 * HROW + ss * 64 + g * 16;
        h8v ahi = *(const h8v*)pa;
        h8v alo = *(const h8v*)(pa + 256);
#pragma unroll
        for (int nf = 0; nf < 4; ++nf) {
          const char* pb = smh + (nc * 64 + nf * 16 + l15) * HROW + ss * 64 + g * 16;
          h8v bhi = *(const h8v*)pb;
          h8v blo = *(const h8v*)(pb + 256);
          oa[nf] = __builtin_amdgcn_mfma_f32_16x16x32_f16(ahi, bhi, oa[nf], 0, 0, 0);
          oa[nf] = __builtin_amdgcn_mfma_f32_16x16x32_f16(ahi, blo, oa[nf], 0, 0, 0);
          oa[nf] = __builtin_amdgcn_mfma_f32_16x16x32_f16(alo, bhi, oa[nf], 0, 0, 0);
        }
      }
      f4v bi = *(const f4v*)((const float*)(ws + OFF_BO) + st * 16 + g * 4);
#pragma unroll
      for (int nf = 0; nf < 4; ++nf) {
        oa[nf] += bi;  // padded classes carry bias -1e30
        float m = fmaxf(fmaxf(oa[nf][0], oa[nf][1]), fmaxf(oa[nf][2], oa[nf][3]));
        m = fmaxf(m, __shfl_xor(m, 16, 64));
        m = fmaxf(m, __shfl_xor(m, 32, 64));
        if (m > 0.5f) conf |= 1u << (shift + nf);
        o[nf] = oa[nf];
      }
    }
    ++item;
  };

#pragma unroll 1
  for (int L = 0; L < 4; ++L) hidden(L);
  wstage(o0, 0, 0);
#pragma unroll 1
  for (int L = 4; L < 9; ++L) hidden(L);
  wstage(o1, 1, 4);
#pragma unroll 1
  for (int L = 9; L < 14; ++L) hidden(L);
  wstage(o2, 2, 8);

  if (mr == 0) {  // early-exit select + store
#pragma unroll
    for (int nf = 0; nf < 4; ++nf) {
      bool c0 = (conf >> nf) & 1u, c1 = (conf >> (4 + nf)) & 1u;
      f4v r;
#pragma unroll
      for (int j = 0; j < 4; ++j) r[j] = c0 ? o0[nf][j] : (c1 ? o1[nf][j] : o2[nf][j]);
      float* dp = out + (size_t)(tile * 128 + nc * 64 + nf * 16 + l15) * 10;
      if (g == 0) {
        *(float2*)(dp) = make_float2(r[0], r[1]);
        *(float2*)(dp + 2) = make_float2(r[2], r[3]);
      } else if (g == 1) {
        *(float2*)(dp + 4) = make_float2(r[0], r[1]);
        *(float2*)(dp + 6) = make_float2(r[2], r[3]);
      } else if (g == 2) {
        *(float2*)(dp + 8) = make_float2(r[0], r[1]);
      }
    }
  }
}

// ---------------------------------------------------------------------------
extern "C" void kernel_launch(void* const* d_in, const int* in_sizes, int n_in,
                              void* d_out, int out_size, void* d_ws, size_t ws_size,
                              hipStream_t stream) {
  (void)in_sizes; (void)n_in; (void)out_size; (void)ws_size;
  const float* x     = (const float*)d_in[0];
  const float* w_in  = (const float*)d_in[1];
  const float* b_in  = (const float*)d_in[2];
  const float* w_hid = (const float*)d_in[3];
  const float* b_hid = (const float*)d_in[4];
  const float* w_out = (const float*)d_in[5];
  const float* b_out = (const float*)d_in[6];
  float* out = (float*)d_out;
  char* ws = (char*)d_ws;

  (void)hipFuncSetAttribute((const void*)fused_k,
                            hipFuncAttributeMaxDynamicSharedMemorySize, SMEM_BYTES);

  prep_k<<<315, 256, 0, stream>>>(w_in, b_in, w_hid, b_hid, w_out, b_out, ws);
  fused_k<<<512, 256, SMEM_BYTES, stream>>>(x, ws, out);
}